// Round 1
// 123.771 us; speedup vs baseline: 1.0439x; 1.0439x over previous
//
#include <hip/hip_runtime.h>

// pred_vol (1,1,64,512,512) fp32; thresh 0.5; 9x9x9 max-pool NMS.
// Identity: thr is monotone and the window contains the center, so
// reference output == (c > 0.5 && c == max999_raw(x)) ? c : 0.
//
// v2 (this round): separable-max restructure, H-first.
//  - Stage RAW plane rows into LDS via global_load_lds dwordx4 (3 per
//    thread/step, linear dest) instead of 9 duplicated global loads
//    (old: left/center/right per row = 3x column redundancy through L1).
//  - Vertical 9-max from LDS at own column (9 ds_read_b128, conflict-free),
//    stage col-max row, horizontal 9-window via prefix/suffix (2 reads).
//  - D-window via 8-slot register ring (unchanged).
// VMEM instrs/thread/step: 11 -> ~4.5. LDS pipe (12 b128/step) now binds.
static constexpr int Dd = 64;
static constexpr int Hh = 512;
static constexpr int Ww = 512;
static constexpr int RAD = 4;
static constexpr float THRESH_V = 0.5f;
static constexpr int W4 = Ww / 4;           // 128 float4 per row
static constexpr int PLANE4 = Hh * W4;      // 65536 float4 per D-plane

static constexpr int TH = 4;                // output h-rows per block
static constexpr int DC = 16;               // output d-planes per block
static constexpr int ROWS = TH + 2 * RAD;   // 12 staged raw rows per plane
static constexpr int STEPS = DC + 2 * RAD;  // 24 d-steps per block
static constexpr int NBLK = (Hh / TH) * (Dd / DC);  // 512 blocks (2/CU)

typedef float nf4 __attribute__((ext_vector_type(4)));

__device__ __forceinline__ float4 f4max(float4 a, float4 b) {
    return make_float4(fmaxf(a.x, b.x), fmaxf(a.y, b.y), fmaxf(a.z, b.z), fmaxf(a.w, b.w));
}
__device__ __forceinline__ int iclamp(int v, int lo, int hi) {
    return v < lo ? lo : (v > hi ? hi : v);
}

// Barriers never drain the cross-step global_load_lds prefetch except by a
// counted vmcnt. lgkmcnt(0) orders LDS traffic only.
#define BAR_VM(N) asm volatile("s_waitcnt vmcnt(" #N ") lgkmcnt(0)\n\ts_barrier" ::: "memory")
#define BAR_LDS() asm volatile("s_waitcnt lgkmcnt(0)\n\ts_barrier" ::: "memory")

// Direct global->LDS DMA, 16B per lane, dest = wave-uniform base + lane*16.
__device__ __forceinline__ void load_lds16(const float4* g, float4* l) {
    __builtin_amdgcn_global_load_lds(
        (const __attribute__((address_space(1))) void*)g,
        (__attribute__((address_space(3))) void*)l, 16, 0, 0);
}

// (512,2): min-blocks semantics -> 2 blocks/CU, 128-VGPR cap (known good).
__global__ __launch_bounds__(512, 2)
void fused_nms_k(const float4* __restrict__ x4, float4* __restrict__ o4) {
    // raw rows double-buffered: 2 * 12 * 128 * 16B = 48 KB; col-max rows 8 KB.
    __shared__ float4 braw[2][ROWS * W4];
    __shared__ float4 bcol[TH * W4];

    const int tid  = threadIdx.x;
    const int w4   = tid & (W4 - 1);   // 0..127
    const int hr   = tid >> 7;         // 0..3 (output row within block)
    const int wid  = tid >> 6;         // wave 0..7
    const int lane = tid & 63;

    // XCD swizzle: band = blockIdx&7 -> h-band of 64 rows stays on one XCD's L2
    const int b    = blockIdx.x;
    const int band = b & 7;
    const int rest = b >> 3;           // 0..63
    const int ht   = band * 16 + (rest & 15);  // 0..127
    const int dc   = rest >> 4;        // 0..3
    const int h0   = ht * TH;
    const int d0   = dc * DC;

    const int colm = w4 ? w4 - 1 : 0;
    const int colp = (w4 < W4 - 1) ? w4 + 1 : W4 - 1;
    const int outrow = (h0 + hr) * W4 + w4;

    // Staging descriptors: 24 segments (12 rows x 2 half-rows), 3 per wave.
    // goff = per-lane float4 offset within a plane; loff = wave-uniform LDS slot.
    int goff[3], loff[3];
#pragma unroll
    for (int k = 0; k < 3; ++k) {
        const int s    = wid + 8 * k;          // 0..23
        const int row  = s >> 1;               // 0..11
        const int half = s & 1;                // 0/1
        const int gh   = iclamp(h0 - RAD + row, 0, Hh - 1);
        goff[k] = gh * W4 + half * 64 + lane;
        loff[k] = row * W4 + half * 64;
    }

    auto stage = [&](int t, int par) {
        const int gd = iclamp(d0 - RAD + t, 0, Dd - 1);
        const float4* pl = x4 + (size_t)gd * PLANE4;
#pragma unroll
        for (int k = 0; k < 3; ++k)
            load_lds16(pl + goff[k], &braw[par][loff[k]]);
    };

    // Slot ring: R[t % 8] holds the HxW-maxed row of plane t, overwritten
    // AFTER being consumed by the emit for plane t-8.
    float4 R[8];

    // One d-step. slot/par/emit/emitPrev compile-time at every call site.
    auto body = [&](int t, int slot, int par, bool emit, bool emitPrev) {
        // Raw plane t is ready once our 3 prefetch loads have landed. The only
        // VMEM op issued after them (previous step) was the output store, so
        // vmcnt(1) gates the loads without draining the store.
        if (emitPrev) BAR_VM(1); else BAR_VM(0);

        // (1) center load FIRST (so its consumption wait is a counted vmcnt
        //     that leaves the prefetch in flight), then next-plane prefetch.
        float4 cen;
        if (emit) {
            cen = x4[(size_t)(d0 + t - 2 * RAD) * PLANE4 + outrow];
            __builtin_amdgcn_sched_barrier(0);  // keep cen issued before stage
        }
        if (t + 1 < STEPS) stage(t + 1, par ^ 1);

        // (2) vertical 9-window max at this thread's column (rows hr..hr+8)
        const float4* Bc = &braw[par][hr * W4 + w4];
        float4 m = f4max(Bc[0 * W4], Bc[1 * W4]);
        m = f4max(m, f4max(Bc[2 * W4], Bc[3 * W4]));
        m = f4max(m, f4max(Bc[4 * W4], Bc[5 * W4]));
        m = f4max(m, f4max(Bc[6 * W4], Bc[7 * W4]));
        m = f4max(m, Bc[8 * W4]);
        bcol[hr * W4 + w4] = m;
        BAR_LDS();

        // (3) horizontal 9-window from the col-max row via prefix/suffix
        const float4 lmv = bcol[hr * W4 + colm];
        const float4 rmv = bcol[hr * W4 + colp];
        const float l3 = lmv.w, l2 = fmaxf(lmv.z, l3), l1 = fmaxf(lmv.y, l2), l0 = fmaxf(lmv.x, l1);
        const float core = fmaxf(fmaxf(m.x, m.y), fmaxf(m.z, m.w));
        const float r0 = rmv.x, r1 = fmaxf(r0, rmv.y), r2 = fmaxf(r1, rmv.z), r3 = fmaxf(r2, rmv.w);
        float4 pm;
        pm.x = fmaxf(l0, fmaxf(core, r0));
        pm.y = fmaxf(l1, fmaxf(core, r1));
        pm.z = fmaxf(l2, fmaxf(core, r2));
        pm.w = fmaxf(l3, fmaxf(core, r3));

        // (4) emit plane t-8: D-window-9 = max(8 ring slots, current pm)
        if (emit) {
            float4 mm = pm;
#pragma unroll
            for (int i = 0; i < 8; ++i) mm = f4max(mm, R[i]);
            nf4 q;
            q.x = (cen.x > THRESH_V && cen.x == mm.x) ? cen.x : 0.0f;
            q.y = (cen.y > THRESH_V && cen.y == mm.y) ? cen.y : 0.0f;
            q.z = (cen.z > THRESH_V && cen.z == mm.z) ? cen.z : 0.0f;
            q.w = (cen.w > THRESH_V && cen.w == mm.w) ? cen.w : 0.0f;
            __builtin_nontemporal_store(
                q, (nf4*)&o4[(size_t)(d0 + t - 2 * RAD) * PLANE4 + outrow]);
        }
        R[slot] = pm;  // overwrite after use
    };

    // Prologue: planes d0-4 .. d0+3 (clamped) fill the ring, no outputs.
    stage(0, 0);
#pragma unroll
    for (int t = 0; t < 8; ++t) body(t, t, t & 1, false, false);
    // Main: 16 emitting steps; fully unrolled so slot/par are static.
    body(8, 0, 0, true, false);   // step 7 issued no store -> vmcnt(0)
#pragma unroll
    for (int j = 1; j < 8; ++j) body(8 + j, j, j & 1, true, true);
#pragma unroll
    for (int j = 0; j < 8; ++j) body(16 + j, j, j & 1, true, true);
}

extern "C" void kernel_launch(void* const* d_in, const int* in_sizes, int n_in,
                              void* d_out, int out_size, void* d_ws, size_t ws_size,
                              hipStream_t stream) {
    const float4* x4 = (const float4*)d_in[0];
    float4* out4 = (float4*)d_out;
    (void)d_ws; (void)ws_size; (void)in_sizes; (void)n_in; (void)out_size;
    fused_nms_k<<<dim3(NBLK), dim3(512), 0, stream>>>(x4, out4);
}